// Round 1
// baseline (625.928 us; speedup 1.0000x reference)
//
#include <hip/hip_runtime.h>
#include <hip/hip_bf16.h>

#define DEV static __device__ __forceinline__

typedef __attribute__((ext_vector_type(4))) float f32x4;
typedef __attribute__((ext_vector_type(8))) short short8;
typedef __attribute__((ext_vector_type(4))) unsigned short u16x4;

#define NB 4
#define NT 2048
#define NDM 1024
#define NH 16
#define NDH 64
#define NM (NB * NT)  // 8192 rows

DEV float bf2f(unsigned short u) {
  union { unsigned int i; float f; } x;
  x.i = ((unsigned int)u) << 16;
  return x.f;
}
DEV unsigned short f2bf(float f) {
  __hip_bfloat16 h = __float2bfloat16(f);
  return *reinterpret_cast<unsigned short*>(&h);
}

// ---------------- f32 -> bf16 convert (n multiple of 8) ----------------
__global__ __launch_bounds__(256) void k_cvt_bf16(const float* __restrict__ in,
                                                  unsigned short* __restrict__ out,
                                                  int n8) {
  int i = blockIdx.x * 256 + threadIdx.x;
  if (i >= n8) return;
  const f32x4* p = (const f32x4*)(in + (size_t)i * 8);
  f32x4 a = p[0], b = p[1];
  short8 o;
  o[0] = (short)f2bf(a[0]); o[1] = (short)f2bf(a[1]);
  o[2] = (short)f2bf(a[2]); o[3] = (short)f2bf(a[3]);
  o[4] = (short)f2bf(b[0]); o[5] = (short)f2bf(b[1]);
  o[6] = (short)f2bf(b[2]); o[7] = (short)f2bf(b[3]);
  *(short8*)(out + (size_t)i * 8) = o;
}

// ---------------- GEMM: C[M][N] = A[M][K] @ B[N][K]^T + bias ----------------
// m97 structure: 128x128 tile, BK=32, global_load_lds w=16, 4 waves x (4x4) 16x16x32 MFMA
template <int OUT_BF16>
__global__ __launch_bounds__(256) void k_gemm_bt(const unsigned short* __restrict__ A,
                                                 const unsigned short* __restrict__ Bw,
                                                 const float* __restrict__ bias,
                                                 void* __restrict__ Cout,
                                                 int M, int N, int K) {
  __shared__ unsigned short lA[128 * 32];
  __shared__ unsigned short lB[128 * 32];
  const int tid = threadIdx.x;
  const int lane = tid & 63;
  const int wave = tid >> 6;
  const int wr = (wave >> 1) * 64;
  const int wc = (wave & 1) * 64;
  const int lq = lane & 15;
  const int lk = (lane >> 4) * 8;
  const int bn = blockIdx.x, bm = blockIdx.y;

  const unsigned short* Ab = A + (size_t)bm * 128 * K;
  const unsigned short* Bb = Bw + (size_t)bn * 128 * K;
  const int r0 = tid >> 2;
  const int c0 = (tid & 3) * 8;

  f32x4 acc[4][4] = {};

  for (int k0 = 0; k0 < K; k0 += 32) {
    __syncthreads();  // previous iter's LDS reads done before overwrite
    __builtin_amdgcn_global_load_lds(
        (const __attribute__((address_space(1))) void*)(Ab + (size_t)r0 * K + k0 + c0),
        (__attribute__((address_space(3))) void*)(lA + tid * 8), 16, 0, 0);
    __builtin_amdgcn_global_load_lds(
        (const __attribute__((address_space(1))) void*)(Ab + (size_t)(r0 + 64) * K + k0 + c0),
        (__attribute__((address_space(3))) void*)(lA + 2048 + tid * 8), 16, 0, 0);
    __builtin_amdgcn_global_load_lds(
        (const __attribute__((address_space(1))) void*)(Bb + (size_t)r0 * K + k0 + c0),
        (__attribute__((address_space(3))) void*)(lB + tid * 8), 16, 0, 0);
    __builtin_amdgcn_global_load_lds(
        (const __attribute__((address_space(1))) void*)(Bb + (size_t)(r0 + 64) * K + k0 + c0),
        (__attribute__((address_space(3))) void*)(lB + 2048 + tid * 8), 16, 0, 0);
    __syncthreads();  // drains vmcnt

    short8 af[4], bf[4];
#pragma unroll
    for (int i = 0; i < 4; ++i) af[i] = *(const short8*)&lA[(wr + i * 16 + lq) * 32 + lk];
#pragma unroll
    for (int j = 0; j < 4; ++j) bf[j] = *(const short8*)&lB[(wc + j * 16 + lq) * 32 + lk];
#pragma unroll
    for (int i = 0; i < 4; ++i)
#pragma unroll
      for (int j = 0; j < 4; ++j)
        acc[i][j] = __builtin_amdgcn_mfma_f32_16x16x32_bf16(af[i], bf[j], acc[i][j], 0, 0, 0);
  }

  // epilogue: C/D layout col = lane&15, row = (lane>>4)*4 + r
  const int rowb = bm * 128 + wr + (lane >> 4) * 4;
  const int colb = bn * 128 + wc + lq;
#pragma unroll
  for (int i = 0; i < 4; ++i) {
#pragma unroll
    for (int j = 0; j < 4; ++j) {
      const int col = colb + j * 16;
      const float bs = bias[col];
#pragma unroll
      for (int r = 0; r < 4; ++r) {
        const size_t idx = (size_t)(rowb + i * 16 + r) * N + col;
        const float v = acc[i][j][r] + bs;
        if (OUT_BF16) ((unsigned short*)Cout)[idx] = f2bf(v);
        else          ((float*)Cout)[idx] = v;
      }
    }
  }
}

// ---------------- RoPE table: tab[t][i] = (cos, sin)(t * theta^{-i/32}) ----------------
__global__ __launch_bounds__(256) void k_rope_table(float2* __restrict__ tab) {
  int i = blockIdx.x * 256 + threadIdx.x;  // NT*32
  int t = i >> 5, f = i & 31;
  float inv = powf(10000.0f, -(float)f / 32.0f);
  float ang = (float)t * inv;
  tab[i] = make_float2(cosf(ang), sinf(ang));
}

// ---------------- RoPE apply + head transpose: [B*T][DM] -> [B][H][T][DH] ----------------
template <int SCALE>  // SCALE: multiply by 1/sqrt(DH) (for Q)
__global__ __launch_bounds__(256) void k_rope_apply(const unsigned short* __restrict__ in,
                                                    const float2* __restrict__ tab,
                                                    unsigned short* __restrict__ out) {
  int i = blockIdx.x * 256 + threadIdx.x;  // B*T*H threads
  int h = i & 15;
  int m = i >> 4;           // b*T + t
  int t = m & (NT - 1);
  int b = m >> 11;
  const unsigned short* src = in + (size_t)m * NDM + h * NDH;
  unsigned short* dst = out + (((size_t)(b * NH + h)) * NT + t) * NDH;
  const float2* tb = tab + (size_t)t * 32;
#pragma unroll
  for (int c = 0; c < 8; ++c) {
    short8 v = *(const short8*)&src[c * 8];
    short8 o;
#pragma unroll
    for (int p = 0; p < 4; ++p) {
      float x0 = bf2f((unsigned short)v[2 * p]);
      float x1 = bf2f((unsigned short)v[2 * p + 1]);
      float2 cs = tb[c * 4 + p];
      float y0 = x0 * cs.x - x1 * cs.y;
      float y1 = x0 * cs.y + x1 * cs.x;
      if (SCALE) { y0 *= 0.125f; y1 *= 0.125f; }
      o[2 * p] = (short)f2bf(y0);
      o[2 * p + 1] = (short)f2bf(y1);
    }
    *(short8*)&dst[c * 8] = o;
  }
}

// ---------------- V transpose: [B*T][DM] -> Vt[B][H][DH][T] ----------------
__global__ __launch_bounds__(256) void k_v_transpose(const unsigned short* __restrict__ in,
                                                     unsigned short* __restrict__ out) {
  __shared__ unsigned short tile[64][64];
  const int bid = blockIdx.x;
  const int tt = bid & 31;
  const int h = (bid >> 5) & 15;
  const int b = bid >> 9;
  const int t0 = tt * 64;
  const int tid = threadIdx.x;
  // phase 1: load 64(t) x 64(d) tile, coalesced
  {
    const int row = tid >> 3;       // 0..31
    const int cc = (tid & 7) * 8;   // 0..56
#pragma unroll
    for (int s = 0; s < 2; ++s) {
      const int t = row + s * 32;
      short8 v = *(const short8*)&in[((size_t)(b * NT) + t0 + t) * NDM + h * NDH + cc];
      *(short8*)&tile[t][cc] = v;
    }
  }
  __syncthreads();
  // phase 2: write transposed; lane-major along d for LDS, 16 t per thread for stores
  {
    const int d = tid >> 2;   // 0..63
    const int tq = tid & 3;   // 0..3
    unsigned short tmp[16];
#pragma unroll
    for (int j = 0; j < 16; ++j) tmp[j] = tile[tq * 16 + j][d];
    short8 o0, o1;
#pragma unroll
    for (int j = 0; j < 8; ++j) { o0[j] = (short)tmp[j]; o1[j] = (short)tmp[8 + j]; }
    const size_t base = (((size_t)(b * NH + h)) * NDH + d) * NT + t0 + tq * 16;
    *(short8*)&out[base] = o0;
    *(short8*)&out[base + 8] = o1;
  }
}

// ---------------- causal flash attention ----------------
// grid: [B*H * T/64]; 4 waves, each owns 16 q-rows. Q pre-scaled by 1/8.
// Computes S^T = mfma(K, Q) so the k-reduction is in-lane; P via per-wave LDS; O^T = mfma(Vt, Pt).
__global__ __launch_bounds__(256) void k_attn(const unsigned short* __restrict__ Qh,
                                              const unsigned short* __restrict__ Kh,
                                              const unsigned short* __restrict__ Vt,
                                              unsigned short* __restrict__ Ctx) {
  __shared__ unsigned short p_lds[4][16][72];  // per-wave P[q][k], padded stride
  const int tid = threadIdx.x;
  const int wave = tid >> 6, lane = tid & 63;
  const int lq = lane & 15, g = lane >> 4;
  const int qt = blockIdx.x & 31;
  const int bh = blockIdx.x >> 5;
  const int q0 = qt * 64 + wave * 16;

  const unsigned short* Q = Qh + ((size_t)bh * NT + q0) * NDH;
  const unsigned short* K = Kh + (size_t)bh * NT * NDH;
  const unsigned short* V = Vt + (size_t)bh * NDH * NT;

  const short8 qf0 = *(const short8*)&Q[(size_t)lq * NDH + g * 8];
  const short8 qf1 = *(const short8*)&Q[(size_t)lq * NDH + 32 + g * 8];

  f32x4 ot[4] = {};
  float m_run = -1e30f, l_run = 0.0f;

  for (int kv0 = 0; kv0 < q0 + 16; kv0 += 64) {
    // S^T tile: st[f] holds S^T[k = kv0+f*16+g*4+r][q = q0+lq]
    f32x4 st[4];
#pragma unroll
    for (int f = 0; f < 4; ++f) {
      const unsigned short* Kr = K + (size_t)(kv0 + f * 16 + lq) * NDH;
      short8 ka0 = *(const short8*)&Kr[g * 8];
      short8 ka1 = *(const short8*)&Kr[32 + g * 8];
      f32x4 s = {};
      s = __builtin_amdgcn_mfma_f32_16x16x32_bf16(ka0, qf0, s, 0, 0, 0);
      s = __builtin_amdgcn_mfma_f32_16x16x32_bf16(ka1, qf1, s, 0, 0, 0);
      st[f] = s;
    }
    if (kv0 + 64 > q0) {  // diagonal block: causal mask k > q
      const int qg = q0 + lq;
#pragma unroll
      for (int f = 0; f < 4; ++f)
#pragma unroll
        for (int r = 0; r < 4; ++r)
          if (kv0 + f * 16 + g * 4 + r > qg) st[f][r] = -1e30f;
    }
    // row max: 16 in-lane + reduce over lanes sharing q (xor 16, 32)
    float mx = -1e30f;
#pragma unroll
    for (int f = 0; f < 4; ++f)
#pragma unroll
      for (int r = 0; r < 4; ++r) mx = fmaxf(mx, st[f][r]);
    mx = fmaxf(mx, __shfl_xor(mx, 16));
    mx = fmaxf(mx, __shfl_xor(mx, 32));
    const float m_new = fmaxf(m_run, mx);
    const float alpha = __expf(m_run - m_new);
    float ps = 0.0f;
#pragma unroll
    for (int f = 0; f < 4; ++f) {
      u16x4 pk;
#pragma unroll
      for (int r = 0; r < 4; ++r) {
        const float p = __expf(st[f][r] - m_new);
        ps += p;
        pk[r] = f2bf(p);
      }
      *(u16x4*)&p_lds[wave][lq][f * 16 + g * 4] = pk;  // P[q=lq][k=f*16+g*4..]
    }
    ps += __shfl_xor(ps, 16);
    ps += __shfl_xor(ps, 32);
    l_run = l_run * alpha + ps;
    m_run = m_new;
#pragma unroll
    for (int f = 0; f < 4; ++f) {
      ot[f][0] *= alpha; ot[f][1] *= alpha; ot[f][2] *= alpha; ot[f][3] *= alpha;
    }
    // PV: Ot[d][q] += Vt_tile * Pt ; B-frag of Pt read back from LDS
    const short8 pb0 = *(const short8*)&p_lds[wave][lq][g * 8];
    const short8 pb1 = *(const short8*)&p_lds[wave][lq][32 + g * 8];
#pragma unroll
    for (int f = 0; f < 4; ++f) {
      const unsigned short* Vr = V + (size_t)(f * 16 + lq) * NT + kv0;
      short8 va0 = *(const short8*)&Vr[g * 8];
      short8 va1 = *(const short8*)&Vr[32 + g * 8];
      ot[f] = __builtin_amdgcn_mfma_f32_16x16x32_bf16(va0, pb0, ot[f], 0, 0, 0);
      ot[f] = __builtin_amdgcn_mfma_f32_16x16x32_bf16(va1, pb1, ot[f], 0, 0, 0);
    }
  }

  const float inv_l = 1.0f / l_run;
  const int b = bh >> 4, h = bh & 15;
  unsigned short* dst = Ctx + ((size_t)(b * NT) + q0 + lq) * NDM + h * NDH;
#pragma unroll
  for (int f = 0; f < 4; ++f) {
    u16x4 o;
#pragma unroll
    for (int r = 0; r < 4; ++r) o[r] = f2bf(ot[f][r] * inv_l);
    *(u16x4*)&dst[f * 16 + g * 4] = o;  // d = f*16 + g*4 + r
  }
}

extern "C" void kernel_launch(void* const* d_in, const int* in_sizes, int n_in,
                              void* d_out, int out_size, void* d_ws, size_t ws_size,
                              hipStream_t stream) {
  const float* x  = (const float*)d_in[0];
  const float* Wq = (const float*)d_in[1];
  const float* bq = (const float*)d_in[2];
  const float* Wk = (const float*)d_in[3];
  const float* bk = (const float*)d_in[4];
  const float* Wv = (const float*)d_in[5];
  const float* bv = (const float*)d_in[6];
  const float* Wo = (const float*)d_in[7];
  const float* bo = (const float*)d_in[8];

  char* ws = (char*)d_ws;
  const size_t MB = 1024 * 1024;
  if (ws_size < 105 * MB) return;  // need ~104.5 MB

  unsigned short* XB   = (unsigned short*)(ws + 0);        // 16MB; reused as VT
  unsigned short* WQB  = (unsigned short*)(ws + 16 * MB);
  unsigned short* WKB  = (unsigned short*)(ws + 18 * MB);
  unsigned short* WVB  = (unsigned short*)(ws + 20 * MB);
  unsigned short* WOB  = (unsigned short*)(ws + 22 * MB);
  unsigned short* QBUF = (unsigned short*)(ws + 24 * MB);  // 16MB; reused as CTX
  unsigned short* KBUF = (unsigned short*)(ws + 40 * MB);
  unsigned short* VBUF = (unsigned short*)(ws + 56 * MB);
  unsigned short* QH   = (unsigned short*)(ws + 72 * MB);
  unsigned short* KH   = (unsigned short*)(ws + 88 * MB);
  float2* TAB          = (float2*)(ws + 104 * MB);         // 512KB
  unsigned short* VT = XB;
  unsigned short* CTX = QBUF;

  // converts
  k_cvt_bf16<<<(NM * NDM / 8) / 256, 256, 0, stream>>>(x, XB, NM * NDM / 8);
  k_cvt_bf16<<<(NDM * NDM / 8) / 256, 256, 0, stream>>>(Wq, WQB, NDM * NDM / 8);
  k_cvt_bf16<<<(NDM * NDM / 8) / 256, 256, 0, stream>>>(Wk, WKB, NDM * NDM / 8);
  k_cvt_bf16<<<(NDM * NDM / 8) / 256, 256, 0, stream>>>(Wv, WVB, NDM * NDM / 8);
  k_cvt_bf16<<<(NDM * NDM / 8) / 256, 256, 0, stream>>>(Wo, WOB, NDM * NDM / 8);

  // QKV projections
  dim3 gg(NDM / 128, NM / 128);
  k_gemm_bt<1><<<gg, 256, 0, stream>>>(XB, WQB, bq, QBUF, NM, NDM, NDM);
  k_gemm_bt<1><<<gg, 256, 0, stream>>>(XB, WKB, bk, KBUF, NM, NDM, NDM);
  k_gemm_bt<1><<<gg, 256, 0, stream>>>(XB, WVB, bv, VBUF, NM, NDM, NDM);

  // rope + transposes
  k_rope_table<<<(NT * 32) / 256, 256, 0, stream>>>(TAB);
  k_rope_apply<1><<<(NB * NT * NH) / 256, 256, 0, stream>>>(QBUF, TAB, QH);
  k_rope_apply<0><<<(NB * NT * NH) / 256, 256, 0, stream>>>(KBUF, TAB, KH);
  k_v_transpose<<<NB * NH * (NT / 64), 256, 0, stream>>>(VBUF, VT);

  // attention
  k_attn<<<NB * NH * (NT / 64), 256, 0, stream>>>(QH, KH, VT, CTX);

  // output projection (f32 out)
  k_gemm_bt<0><<<gg, 256, 0, stream>>>(CTX, WOB, bo, d_out, NM, NDM, NDM);
}

// Round 2
// 296.625 us; speedup vs baseline: 2.1102x; 2.1102x over previous
//
#include <hip/hip_runtime.h>
#include <hip/hip_bf16.h>

#define DEV static __device__ __forceinline__

typedef __attribute__((ext_vector_type(4))) float f32x4;
typedef __attribute__((ext_vector_type(8))) short short8;
typedef __attribute__((ext_vector_type(4))) unsigned short u16x4;

#define NB 4
#define NT 2048
#define NDM 1024
#define NH 16
#define NDH 64
#define NM (NB * NT)  // 8192 rows

DEV float bf2f(unsigned short u) {
  union { unsigned int i; float f; } x;
  x.i = ((unsigned int)u) << 16;
  return x.f;
}
DEV unsigned short f2bf(float f) {
  __hip_bfloat16 h = __float2bfloat16(f);
  return *reinterpret_cast<unsigned short*>(&h);
}

// ---------------- f32 -> bf16 convert (n multiple of 8) ----------------
__global__ __launch_bounds__(256) void k_cvt_bf16(const float* __restrict__ in,
                                                  unsigned short* __restrict__ out,
                                                  int n8) {
  int i = blockIdx.x * 256 + threadIdx.x;
  if (i >= n8) return;
  const f32x4* p = (const f32x4*)(in + (size_t)i * 8);
  f32x4 a = p[0], b = p[1];
  short8 o;
  o[0] = (short)f2bf(a[0]); o[1] = (short)f2bf(a[1]);
  o[2] = (short)f2bf(a[2]); o[3] = (short)f2bf(a[3]);
  o[4] = (short)f2bf(b[0]); o[5] = (short)f2bf(b[1]);
  o[6] = (short)f2bf(b[2]); o[7] = (short)f2bf(b[3]);
  *(short8*)(out + (size_t)i * 8) = o;
}

// ---------------- GEMM: C[M][N] = A[M][K] @ B[N][K]^T + bias ----------------
template <int OUT_BF16>
__global__ __launch_bounds__(256) void k_gemm_bt(const unsigned short* __restrict__ A,
                                                 const unsigned short* __restrict__ Bw,
                                                 const float* __restrict__ bias,
                                                 void* __restrict__ Cout,
                                                 int M, int N, int K) {
  __shared__ unsigned short lA[128 * 32];
  __shared__ unsigned short lB[128 * 32];
  const int tid = threadIdx.x;
  const int lane = tid & 63;
  const int wave = tid >> 6;
  const int wr = (wave >> 1) * 64;
  const int wc = (wave & 1) * 64;
  const int lq = lane & 15;
  const int lk = (lane >> 4) * 8;

  // XCD-aware bijective swizzle (nwg = 512, divisible by 8)
  unsigned int nbx = gridDim.x;
  unsigned int bid = blockIdx.y * nbx + blockIdx.x;
  unsigned int cpx = (nbx * gridDim.y) >> 3;
  unsigned int swz = (bid & 7) * cpx + (bid >> 3);
  const int bn = swz % nbx, bm = swz / nbx;

  const unsigned short* Ab = A + (size_t)bm * 128 * K;
  const unsigned short* Bb = Bw + (size_t)bn * 128 * K;
  const int r0 = tid >> 2;
  const int c0 = (tid & 3) * 8;

  f32x4 acc[4][4] = {};

  for (int k0 = 0; k0 < K; k0 += 32) {
    __syncthreads();  // previous iter's LDS reads done before overwrite
    __builtin_amdgcn_global_load_lds(
        (const __attribute__((address_space(1))) void*)(Ab + (size_t)r0 * K + k0 + c0),
        (__attribute__((address_space(3))) void*)(lA + tid * 8), 16, 0, 0);
    __builtin_amdgcn_global_load_lds(
        (const __attribute__((address_space(1))) void*)(Ab + (size_t)(r0 + 64) * K + k0 + c0),
        (__attribute__((address_space(3))) void*)(lA + 2048 + tid * 8), 16, 0, 0);
    __builtin_amdgcn_global_load_lds(
        (const __attribute__((address_space(1))) void*)(Bb + (size_t)r0 * K + k0 + c0),
        (__attribute__((address_space(3))) void*)(lB + tid * 8), 16, 0, 0);
    __builtin_amdgcn_global_load_lds(
        (const __attribute__((address_space(1))) void*)(Bb + (size_t)(r0 + 64) * K + k0 + c0),
        (__attribute__((address_space(3))) void*)(lB + 2048 + tid * 8), 16, 0, 0);
    __syncthreads();  // drains vmcnt

    short8 af[4], bf[4];
#pragma unroll
    for (int i = 0; i < 4; ++i) af[i] = *(const short8*)&lA[(wr + i * 16 + lq) * 32 + lk];
#pragma unroll
    for (int j = 0; j < 4; ++j) bf[j] = *(const short8*)&lB[(wc + j * 16 + lq) * 32 + lk];
#pragma unroll
    for (int i = 0; i < 4; ++i)
#pragma unroll
      for (int j = 0; j < 4; ++j)
        acc[i][j] = __builtin_amdgcn_mfma_f32_16x16x32_bf16(af[i], bf[j], acc[i][j], 0, 0, 0);
  }

  // epilogue: C/D layout col = lane&15, row = (lane>>4)*4 + r
  const int rowb = bm * 128 + wr + (lane >> 4) * 4;
  const int colb = bn * 128 + wc + lq;
#pragma unroll
  for (int i = 0; i < 4; ++i) {
#pragma unroll
    for (int j = 0; j < 4; ++j) {
      const int col = colb + j * 16;
      const float bs = bias[col];
#pragma unroll
      for (int r = 0; r < 4; ++r) {
        const size_t idx = (size_t)(rowb + i * 16 + r) * N + col;
        const float v = acc[i][j][r] + bs;
        if (OUT_BF16) ((unsigned short*)Cout)[idx] = f2bf(v);
        else          ((float*)Cout)[idx] = v;
      }
    }
  }
}

// ---------------- RoPE table ----------------
__global__ __launch_bounds__(256) void k_rope_table(float2* __restrict__ tab) {
  int i = blockIdx.x * 256 + threadIdx.x;  // NT*32
  int t = i >> 5, f = i & 31;
  float inv = powf(10000.0f, -(float)f / 32.0f);
  float ang = (float)t * inv;
  tab[i] = make_float2(cosf(ang), sinf(ang));
}

// ---------------- RoPE apply + head transpose: [B*T][DM] -> [B][H][T][DH] ----------------
// SCALE: Q gets 1/sqrt(DH) * log2(e) folded in, so attention softmax runs in exp2 domain.
template <int SCALE>
__global__ __launch_bounds__(256) void k_rope_apply(const unsigned short* __restrict__ in,
                                                    const float2* __restrict__ tab,
                                                    unsigned short* __restrict__ out) {
  int i = blockIdx.x * 256 + threadIdx.x;  // B*T*H threads
  int h = i & 15;
  int m = i >> 4;           // b*T + t
  int t = m & (NT - 1);
  int b = m >> 11;
  const unsigned short* src = in + (size_t)m * NDM + h * NDH;
  unsigned short* dst = out + (((size_t)(b * NH + h)) * NT + t) * NDH;
  const float2* tb = tab + (size_t)t * 32;
  const float qs = 0.125f * 1.44269504088896f;
#pragma unroll
  for (int c = 0; c < 8; ++c) {
    short8 v = *(const short8*)&src[c * 8];
    short8 o;
#pragma unroll
    for (int p = 0; p < 4; ++p) {
      float x0 = bf2f((unsigned short)v[2 * p]);
      float x1 = bf2f((unsigned short)v[2 * p + 1]);
      float2 cs = tb[c * 4 + p];
      float y0 = x0 * cs.x - x1 * cs.y;
      float y1 = x0 * cs.y + x1 * cs.x;
      if (SCALE) { y0 *= qs; y1 *= qs; }
      o[2 * p] = (short)f2bf(y0);
      o[2 * p + 1] = (short)f2bf(y1);
    }
    *(short8*)&dst[c * 8] = o;
  }
}

// ---------------- V transpose: [B*T][DM] -> Vt[B][H][DH][T] ----------------
__global__ __launch_bounds__(256) void k_v_transpose(const unsigned short* __restrict__ in,
                                                     unsigned short* __restrict__ out) {
  __shared__ unsigned short tile[64][64];
  const int bid = blockIdx.x;
  const int tt = bid & 31;
  const int h = (bid >> 5) & 15;
  const int b = bid >> 9;
  const int t0 = tt * 64;
  const int tid = threadIdx.x;
  {
    const int row = tid >> 3;
    const int cc = (tid & 7) * 8;
#pragma unroll
    for (int s = 0; s < 2; ++s) {
      const int t = row + s * 32;
      short8 v = *(const short8*)&in[((size_t)(b * NT) + t0 + t) * NDM + h * NDH + cc];
      *(short8*)&tile[t][cc] = v;
    }
  }
  __syncthreads();
  {
    const int d = tid >> 2;
    const int tq = tid & 3;
    unsigned short tmp[16];
#pragma unroll
    for (int j = 0; j < 16; ++j) tmp[j] = tile[tq * 16 + j][d];
    short8 o0, o1;
#pragma unroll
    for (int j = 0; j < 8; ++j) { o0[j] = (short)tmp[j]; o1[j] = (short)tmp[8 + j]; }
    const size_t base = (((size_t)(b * NH + h)) * NDH + d) * NT + t0 + tq * 16;
    *(short8*)&out[base] = o0;
    *(short8*)&out[base + 8] = o1;
  }
}

// ---------------- causal flash attention (balanced, 32 q-rows/wave) ----------------
// grid: [B*H * 8]; 4 waves/block. Wave w handles 32-row q-tile pairIdx and mirror 63-pairIdx
// (uniform ~33 kv-blocks per wave -> no occupancy decay tail).
// Swapped QK^T (S^T = mfma(K,Q)) keeps the kv-reduction in-lane; Q pre-scaled by log2(e)/8
// so softmax is pure exp2. K double-buffered in registers (ping-pong, no copies).
__global__ __launch_bounds__(256, 2) void k_attn(const unsigned short* __restrict__ Qh,
                                                 const unsigned short* __restrict__ Kh,
                                                 const unsigned short* __restrict__ Vt,
                                                 unsigned short* __restrict__ Ctx) {
  __shared__ unsigned short p_lds[4][32][72];  // per-wave P[q][k], padded stride
  const int tid = threadIdx.x;
  const int wave = tid >> 6, lane = tid & 63;
  const int lq = lane & 15, g = lane >> 4;
  const int pb = blockIdx.x & 7;
  const int bh = blockIdx.x >> 3;
  const int pairIdx = pb * 4 + wave;  // 0..31
  const int b = bh >> 4, h = bh & 15;

  const unsigned short* K = Kh + (size_t)bh * NT * NDH;
  const unsigned short* V = Vt + (size_t)bh * NDH * NT;

  for (int tt = 0; tt < 2; ++tt) {
    const int j = tt ? (63 - pairIdx) : pairIdx;  // 32-row tile index in [0,64)
    const int q0 = j * 32;
    const unsigned short* Q = Qh + ((size_t)bh * NT + q0) * NDH;

    short8 qf[2][2];
#pragma unroll
    for (int s = 0; s < 2; ++s) {
      const unsigned short* Qr = Q + (size_t)(s * 16 + lq) * NDH;
      qf[s][0] = *(const short8*)&Qr[g * 8];
      qf[s][1] = *(const short8*)&Qr[32 + g * 8];
    }

    f32x4 ot[4][2] = {};
    float m_run[2] = {-1e30f, -1e30f};
    float l_run[2] = {0.0f, 0.0f};

    const int nb_kv = (q0 + 32 + 63) >> 6;  // kv blocks of 64

    short8 kfA[4][2], kfB[4][2];
#pragma unroll
    for (int f = 0; f < 4; ++f) {
      const unsigned short* Kr = K + (size_t)(f * 16 + lq) * NDH;
      kfA[f][0] = *(const short8*)&Kr[g * 8];
      kfA[f][1] = *(const short8*)&Kr[32 + g * 8];
    }

    auto body = [&](int kv0, int kv0n, short8 (&kc)[4][2], short8 (&kn)[4][2]) {
      // QK^T: st[f][s][r] = S^T[k=kv0+f*16+g*4+r][q=q0+s*16+lq]  (log2 domain)
      f32x4 st[4][2];
#pragma unroll
      for (int f = 0; f < 4; ++f) {
#pragma unroll
        for (int s = 0; s < 2; ++s) {
          f32x4 t = {};
          t = __builtin_amdgcn_mfma_f32_16x16x32_bf16(kc[f][0], qf[s][0], t, 0, 0, 0);
          t = __builtin_amdgcn_mfma_f32_16x16x32_bf16(kc[f][1], qf[s][1], t, 0, 0, 0);
          st[f][s] = t;
        }
      }
      // prefetch next K block (clamped) into the other buffer
#pragma unroll
      for (int f = 0; f < 4; ++f) {
        const unsigned short* Kr = K + (size_t)(kv0n + f * 16 + lq) * NDH;
        kn[f][0] = *(const short8*)&Kr[g * 8];
        kn[f][1] = *(const short8*)&Kr[32 + g * 8];
      }
      // V loads for this block (independent of softmax)
      short8 vf[4][2];
#pragma unroll
      for (int f = 0; f < 4; ++f) {
        const unsigned short* Vr = V + (size_t)(f * 16 + lq) * NT + kv0;
        vf[f][0] = *(const short8*)&Vr[g * 8];
        vf[f][1] = *(const short8*)&Vr[32 + g * 8];
      }
      // causal mask (final block only)
      if (kv0 + 64 > q0) {
#pragma unroll
        for (int f = 0; f < 4; ++f)
#pragma unroll
          for (int s = 0; s < 2; ++s)
#pragma unroll
            for (int r = 0; r < 4; ++r)
              if (kv0 + f * 16 + g * 4 + r > q0 + s * 16 + lq) st[f][s][r] = -1e30f;
      }
      // online softmax per q-subtile
#pragma unroll
      for (int s = 0; s < 2; ++s) {
        float mx = -1e30f;
#pragma unroll
        for (int f = 0; f < 4; ++f)
#pragma unroll
          for (int r = 0; r < 4; ++r) mx = fmaxf(mx, st[f][s][r]);
        mx = fmaxf(mx, __shfl_xor(mx, 16));
        mx = fmaxf(mx, __shfl_xor(mx, 32));
        const float m_new = fmaxf(m_run[s], mx);
        const float alpha = exp2f(m_run[s] - m_new);
        m_run[s] = m_new;
        float ps = 0.0f;
#pragma unroll
        for (int f = 0; f < 4; ++f) {
          u16x4 pk;
#pragma unroll
          for (int r = 0; r < 4; ++r) {
            const float p = exp2f(st[f][s][r] - m_new);
            ps += p;
            pk[r] = f2bf(p);
          }
          *(u16x4*)&p_lds[wave][s * 16 + lq][f * 16 + g * 4] = pk;
        }
        ps += __shfl_xor(ps, 16);
        ps += __shfl_xor(ps, 32);
        l_run[s] = l_run[s] * alpha + ps;
#pragma unroll
        for (int f = 0; f < 4; ++f) {
          ot[f][s][0] *= alpha; ot[f][s][1] *= alpha;
          ot[f][s][2] *= alpha; ot[f][s][3] *= alpha;
        }
      }
      // PV: Ot[d][q] += Vt * P^T
      short8 pbf[2][2];
#pragma unroll
      for (int s = 0; s < 2; ++s) {
        pbf[s][0] = *(const short8*)&p_lds[wave][s * 16 + lq][g * 8];
        pbf[s][1] = *(const short8*)&p_lds[wave][s * 16 + lq][32 + g * 8];
      }
#pragma unroll
      for (int f = 0; f < 4; ++f)
#pragma unroll
        for (int s = 0; s < 2; ++s) {
          ot[f][s] = __builtin_amdgcn_mfma_f32_16x16x32_bf16(vf[f][0], pbf[s][0], ot[f][s], 0, 0, 0);
          ot[f][s] = __builtin_amdgcn_mfma_f32_16x16x32_bf16(vf[f][1], pbf[s][1], ot[f][s], 0, 0, 0);
        }
    };

    int kb = 0;
    while (kb < nb_kv) {
      int kv0 = kb << 6;
      int kv0n = kv0 + ((kb + 1 < nb_kv) ? 64 : 0);
      body(kv0, kv0n, kfA, kfB);
      ++kb;
      if (kb >= nb_kv) break;
      kv0 = kb << 6;
      kv0n = kv0 + ((kb + 1 < nb_kv) ? 64 : 0);
      body(kv0, kv0n, kfB, kfA);
      ++kb;
    }

    const float inv_l0 = 1.0f / l_run[0];
    const float inv_l1 = 1.0f / l_run[1];
#pragma unroll
    for (int s = 0; s < 2; ++s) {
      const float inv_l = s ? inv_l1 : inv_l0;
      unsigned short* dst = Ctx + ((size_t)(b * NT) + q0 + s * 16 + lq) * NDM + h * NDH;
#pragma unroll
      for (int f = 0; f < 4; ++f) {
        u16x4 o;
#pragma unroll
        for (int r = 0; r < 4; ++r) o[r] = f2bf(ot[f][s][r] * inv_l);
        *(u16x4*)&dst[f * 16 + g * 4] = o;
      }
    }
  }
}

extern "C" void kernel_launch(void* const* d_in, const int* in_sizes, int n_in,
                              void* d_out, int out_size, void* d_ws, size_t ws_size,
                              hipStream_t stream) {
  const float* x  = (const float*)d_in[0];
  const float* Wq = (const float*)d_in[1];
  const float* bq = (const float*)d_in[2];
  const float* Wk = (const float*)d_in[3];
  const float* bk = (const float*)d_in[4];
  const float* Wv = (const float*)d_in[5];
  const float* bv = (const float*)d_in[6];
  const float* Wo = (const float*)d_in[7];
  const float* bo = (const float*)d_in[8];

  char* ws = (char*)d_ws;
  const size_t MB = 1024 * 1024;
  if (ws_size < 105 * MB) return;

  unsigned short* XB   = (unsigned short*)(ws + 0);        // 16MB; reused as VT
  unsigned short* WQB  = (unsigned short*)(ws + 16 * MB);
  unsigned short* WKB  = (unsigned short*)(ws + 18 * MB);
  unsigned short* WVB  = (unsigned short*)(ws + 20 * MB);
  unsigned short* WOB  = (unsigned short*)(ws + 22 * MB);
  unsigned short* QBUF = (unsigned short*)(ws + 24 * MB);  // 16MB; reused as CTX
  unsigned short* KBUF = (unsigned short*)(ws + 40 * MB);
  unsigned short* VBUF = (unsigned short*)(ws + 56 * MB);
  unsigned short* QH   = (unsigned short*)(ws + 72 * MB);
  unsigned short* KH   = (unsigned short*)(ws + 88 * MB);
  float2* TAB          = (float2*)(ws + 104 * MB);         // 512KB
  unsigned short* VT = XB;
  unsigned short* CTX = QBUF;

  // converts
  k_cvt_bf16<<<(NM * NDM / 8) / 256, 256, 0, stream>>>(x, XB, NM * NDM / 8);
  k_cvt_bf16<<<(NDM * NDM / 8) / 256, 256, 0, stream>>>(Wq, WQB, NDM * NDM / 8);
  k_cvt_bf16<<<(NDM * NDM / 8) / 256, 256, 0, stream>>>(Wk, WKB, NDM * NDM / 8);
  k_cvt_bf16<<<(NDM * NDM / 8) / 256, 256, 0, stream>>>(Wv, WVB, NDM * NDM / 8);
  k_cvt_bf16<<<(NDM * NDM / 8) / 256, 256, 0, stream>>>(Wo, WOB, NDM * NDM / 8);

  // QKV projections
  dim3 gg(NDM / 128, NM / 128);
  k_gemm_bt<1><<<gg, 256, 0, stream>>>(XB, WQB, bq, QBUF, NM, NDM, NDM);
  k_gemm_bt<1><<<gg, 256, 0, stream>>>(XB, WKB, bk, KBUF, NM, NDM, NDM);
  k_gemm_bt<1><<<gg, 256, 0, stream>>>(XB, WVB, bv, VBUF, NM, NDM, NDM);

  // rope + transposes
  k_rope_table<<<(NT * 32) / 256, 256, 0, stream>>>(TAB);
  k_rope_apply<1><<<(NB * NT * NH) / 256, 256, 0, stream>>>(QBUF, TAB, QH);
  k_rope_apply<0><<<(NB * NT * NH) / 256, 256, 0, stream>>>(KBUF, TAB, KH);
  k_v_transpose<<<NB * NH * (NT / 64), 256, 0, stream>>>(VBUF, VT);

  // attention (balanced pairing: 64 bh * 8 blocks)
  k_attn<<<NB * NH * 8, 256, 0, stream>>>(QH, KH, VT, CTX);

  // output projection (f32 out)
  k_gemm_bt<0><<<gg, 256, 0, stream>>>(CTX, WOB, bo, d_out, NM, NDM, NDM);
}

// Round 3
// 286.951 us; speedup vs baseline: 2.1813x; 1.0337x over previous
//
#include <hip/hip_runtime.h>
#include <hip/hip_bf16.h>

#define DEV static __device__ __forceinline__

typedef __attribute__((ext_vector_type(4))) float f32x4;
typedef __attribute__((ext_vector_type(16))) float f32x16;
typedef __attribute__((ext_vector_type(8))) short short8;
typedef __attribute__((ext_vector_type(4))) unsigned short u16x4;
typedef __attribute__((ext_vector_type(4))) unsigned int u32x4;

#define NB 4
#define NT 2048
#define NDM 1024
#define NH 16
#define NDH 64
#define NM (NB * NT)  // 8192 rows

DEV float bf2f(unsigned short u) {
  union { unsigned int i; float f; } x;
  x.i = ((unsigned int)u) << 16;
  return x.f;
}
DEV unsigned short f2bf(float f) {
  __hip_bfloat16 h = __float2bfloat16(f);
  return *reinterpret_cast<unsigned short*>(&h);
}
DEV unsigned int pack2bf(float lo, float hi) {
  return ((unsigned int)f2bf(hi) << 16) | (unsigned int)f2bf(lo);
}
DEV short8 mkfrag(unsigned int w0, unsigned int w1, unsigned int w2, unsigned int w3) {
  union { u32x4 u; short8 s; } x;
  x.u[0] = w0; x.u[1] = w1; x.u[2] = w2; x.u[3] = w3;
  return x.s;
}

// ---------------- f32 -> bf16 convert (n multiple of 8) ----------------
__global__ __launch_bounds__(256) void k_cvt_bf16(const float* __restrict__ in,
                                                  unsigned short* __restrict__ out,
                                                  int n8) {
  int i = blockIdx.x * 256 + threadIdx.x;
  if (i >= n8) return;
  const f32x4* p = (const f32x4*)(in + (size_t)i * 8);
  f32x4 a = p[0], b = p[1];
  short8 o;
  o[0] = (short)f2bf(a[0]); o[1] = (short)f2bf(a[1]);
  o[2] = (short)f2bf(a[2]); o[3] = (short)f2bf(a[3]);
  o[4] = (short)f2bf(b[0]); o[5] = (short)f2bf(b[1]);
  o[6] = (short)f2bf(b[2]); o[7] = (short)f2bf(b[3]);
  *(short8*)(out + (size_t)i * 8) = o;
}

// 4 weight matrices in one launch (same size NDM*NDM)
__global__ __launch_bounds__(256) void k_cvt_w(const float* __restrict__ w0, const float* __restrict__ w1,
                                               const float* __restrict__ w2, const float* __restrict__ w3,
                                               unsigned short* __restrict__ o0, unsigned short* __restrict__ o1,
                                               unsigned short* __restrict__ o2, unsigned short* __restrict__ o3) {
  int i = blockIdx.x * 256 + threadIdx.x;  // per-matrix idx (x8 elems)
  int m = blockIdx.y;
  const float* in = (m == 0) ? w0 : (m == 1) ? w1 : (m == 2) ? w2 : w3;
  unsigned short* out = (m == 0) ? o0 : (m == 1) ? o1 : (m == 2) ? o2 : o3;
  const f32x4* p = (const f32x4*)(in + (size_t)i * 8);
  f32x4 a = p[0], b = p[1];
  short8 o;
  o[0] = (short)f2bf(a[0]); o[1] = (short)f2bf(a[1]);
  o[2] = (short)f2bf(a[2]); o[3] = (short)f2bf(a[3]);
  o[4] = (short)f2bf(b[0]); o[5] = (short)f2bf(b[1]);
  o[6] = (short)f2bf(b[2]); o[7] = (short)f2bf(b[3]);
  *(short8*)(out + (size_t)i * 8) = o;
}

// ---------------- GEMM: C[M][N] = A[M][K] @ B[N][K]^T + bias ----------------
template <int OUT_BF16>
__global__ __launch_bounds__(256) void k_gemm_bt(const unsigned short* __restrict__ A,
                                                 const unsigned short* __restrict__ Bw,
                                                 const float* __restrict__ bias,
                                                 void* __restrict__ Cout,
                                                 int M, int N, int K) {
  __shared__ unsigned short lA[128 * 32];
  __shared__ unsigned short lB[128 * 32];
  const int tid = threadIdx.x;
  const int lane = tid & 63;
  const int wave = tid >> 6;
  const int wr = (wave >> 1) * 64;
  const int wc = (wave & 1) * 64;
  const int lq = lane & 15;
  const int lk = (lane >> 4) * 8;

  // XCD-aware bijective swizzle (nwg = 512, divisible by 8)
  unsigned int nbx = gridDim.x;
  unsigned int bid = blockIdx.y * nbx + blockIdx.x;
  unsigned int cpx = (nbx * gridDim.y) >> 3;
  unsigned int swz = (bid & 7) * cpx + (bid >> 3);
  const int bn = swz % nbx, bm = swz / nbx;

  const unsigned short* Ab = A + (size_t)bm * 128 * K;
  const unsigned short* Bb = Bw + (size_t)bn * 128 * K;
  const int r0 = tid >> 2;
  const int c0 = (tid & 3) * 8;

  f32x4 acc[4][4] = {};

  for (int k0 = 0; k0 < K; k0 += 32) {
    __syncthreads();
    __builtin_amdgcn_global_load_lds(
        (const __attribute__((address_space(1))) void*)(Ab + (size_t)r0 * K + k0 + c0),
        (__attribute__((address_space(3))) void*)(lA + tid * 8), 16, 0, 0);
    __builtin_amdgcn_global_load_lds(
        (const __attribute__((address_space(1))) void*)(Ab + (size_t)(r0 + 64) * K + k0 + c0),
        (__attribute__((address_space(3))) void*)(lA + 2048 + tid * 8), 16, 0, 0);
    __builtin_amdgcn_global_load_lds(
        (const __attribute__((address_space(1))) void*)(Bb + (size_t)r0 * K + k0 + c0),
        (__attribute__((address_space(3))) void*)(lB + tid * 8), 16, 0, 0);
    __builtin_amdgcn_global_load_lds(
        (const __attribute__((address_space(1))) void*)(Bb + (size_t)(r0 + 64) * K + k0 + c0),
        (__attribute__((address_space(3))) void*)(lB + 2048 + tid * 8), 16, 0, 0);
    __syncthreads();

    short8 af[4], bf[4];
#pragma unroll
    for (int i = 0; i < 4; ++i) af[i] = *(const short8*)&lA[(wr + i * 16 + lq) * 32 + lk];
#pragma unroll
    for (int j = 0; j < 4; ++j) bf[j] = *(const short8*)&lB[(wc + j * 16 + lq) * 32 + lk];
#pragma unroll
    for (int i = 0; i < 4; ++i)
#pragma unroll
      for (int j = 0; j < 4; ++j)
        acc[i][j] = __builtin_amdgcn_mfma_f32_16x16x32_bf16(af[i], bf[j], acc[i][j], 0, 0, 0);
  }

  const int rowb = bm * 128 + wr + (lane >> 4) * 4;
  const int colb = bn * 128 + wc + lq;
#pragma unroll
  for (int i = 0; i < 4; ++i) {
#pragma unroll
    for (int j = 0; j < 4; ++j) {
      const int col = colb + j * 16;
      const float bs = bias[col];
#pragma unroll
      for (int r = 0; r < 4; ++r) {
        const size_t idx = (size_t)(rowb + i * 16 + r) * N + col;
        const float v = acc[i][j][r] + bs;
        if (OUT_BF16) ((unsigned short*)Cout)[idx] = f2bf(v);
        else          ((float*)Cout)[idx] = v;
      }
    }
  }
}

// ---------------- RoPE table ----------------
__global__ __launch_bounds__(256) void k_rope_table(float2* __restrict__ tab) {
  int i = blockIdx.x * 256 + threadIdx.x;  // NT*32
  int t = i >> 5, f = i & 31;
  float inv = powf(10000.0f, -(float)f / 32.0f);
  float ang = (float)t * inv;
  tab[i] = make_float2(cosf(ang), sinf(ang));
}

// ---------------- RoPE apply + head transpose: [B*T][DM] -> [B][H][T][DH] ----------------
// SCALE: Q gets 1/sqrt(DH) * log2(e) folded in -> attention softmax runs in exp2 domain.
template <int SCALE>
__global__ __launch_bounds__(256) void k_rope_apply(const unsigned short* __restrict__ in,
                                                    const float2* __restrict__ tab,
                                                    unsigned short* __restrict__ out) {
  int i = blockIdx.x * 256 + threadIdx.x;  // B*T*H threads
  int h = i & 15;
  int m = i >> 4;           // b*T + t
  int t = m & (NT - 1);
  int b = m >> 11;
  const unsigned short* src = in + (size_t)m * NDM + h * NDH;
  unsigned short* dst = out + (((size_t)(b * NH + h)) * NT + t) * NDH;
  const float2* tb = tab + (size_t)t * 32;
  const float qs = 0.125f * 1.44269504088896f;
#pragma unroll
  for (int c = 0; c < 8; ++c) {
    short8 v = *(const short8*)&src[c * 8];
    short8 o;
#pragma unroll
    for (int p = 0; p < 4; ++p) {
      float x0 = bf2f((unsigned short)v[2 * p]);
      float x1 = bf2f((unsigned short)v[2 * p + 1]);
      float2 cs = tb[c * 4 + p];
      float y0 = x0 * cs.x - x1 * cs.y;
      float y1 = x0 * cs.y + x1 * cs.x;
      if (SCALE) { y0 *= qs; y1 *= qs; }
      o[2 * p] = (short)f2bf(y0);
      o[2 * p + 1] = (short)f2bf(y1);
    }
    *(short8*)&dst[c * 8] = o;
  }
}

// ---------------- V transpose: [B*T][DM] -> Vt[B][H][DH][T] ----------------
__global__ __launch_bounds__(256) void k_v_transpose(const unsigned short* __restrict__ in,
                                                     unsigned short* __restrict__ out) {
  __shared__ unsigned short tile[64][64];
  const int bid = blockIdx.x;
  const int tt = bid & 31;
  const int h = (bid >> 5) & 15;
  const int b = bid >> 9;
  const int t0 = tt * 64;
  const int tid = threadIdx.x;
  {
    const int row = tid >> 3;
    const int cc = (tid & 7) * 8;
#pragma unroll
    for (int s = 0; s < 2; ++s) {
      const int t = row + s * 32;
      short8 v = *(const short8*)&in[((size_t)(b * NT) + t0 + t) * NDM + h * NDH + cc];
      *(short8*)&tile[t][cc] = v;
    }
  }
  __syncthreads();
  {
    const int d = tid >> 2;
    const int tq = tid & 3;
    unsigned short tmp[16];
#pragma unroll
    for (int j = 0; j < 16; ++j) tmp[j] = tile[tq * 16 + j][d];
    short8 o0, o1;
#pragma unroll
    for (int j = 0; j < 8; ++j) { o0[j] = (short)tmp[j]; o1[j] = (short)tmp[8 + j]; }
    const size_t base = (((size_t)(b * NH + h)) * NDH + d) * NT + t0 + tq * 16;
    *(short8*)&out[base] = o0;
    *(short8*)&out[base + 8] = o1;
  }
}

// ---------------- causal flash attention: 32x32 MFMA, in-register softmax ----------------
// grid: [B*H * 8] remapped so each bh's 8 blocks share one XCD (K/V L2-resident).
// 4 waves/block; wave handles 32-row q-tiles pairIdx and 63-pairIdx (uniform 65 kv-blocks).
// Swapped QK^T: st = mfma32x32(K, Q) -> lane holds S^T[k-halfrow][q=lane&31].
// Softmax fully in-register (log2 domain, defer-max THR=8); PV B-frag built via
// pack + shfl_xor(32) + select (no LDS anywhere).
__global__ __launch_bounds__(256, 2) void k_attn(const unsigned short* __restrict__ Qh,
                                                 const unsigned short* __restrict__ Kh,
                                                 const unsigned short* __restrict__ Vt,
                                                 unsigned short* __restrict__ Ctx) {
  const int tid = threadIdx.x;
  const int wave = tid >> 6, lane = tid & 63;
  const int l31 = lane & 31, hi = lane >> 5;
  const int b0 = blockIdx.x;
  const int bh = (b0 & 7) * 8 + ((b0 >> 3) & 7);  // XCD-local bh grouping
  const int pairIdx = (b0 >> 6) * 4 + wave;       // 0..31
  const int b = bh >> 4, h = bh & 15;

  const unsigned short* K = Kh + (size_t)bh * NT * NDH;
  const unsigned short* V = Vt + (size_t)bh * NDH * NT;

  for (int tt = 0; tt < 2; ++tt) {
    const int j = tt ? (63 - pairIdx) : pairIdx;  // 32-row tile index in [0,64)
    const int q0 = j * 32;
    const int nb = j + 1;  // number of 32-wide kv blocks

    // Q fragment (B-operand): lane holds Q[q0+l31][16s + 8hi + 0..7]
    const unsigned short* Qr = Qh + ((size_t)bh * NT + q0 + l31) * NDH + 8 * hi;
    short8 qf[4];
#pragma unroll
    for (int s = 0; s < 4; ++s) qf[s] = *(const short8*)&Qr[16 * s];

    f32x16 ot0 = {}, ot1 = {};
    float m_run = -1e30f, l_run = 0.0f;

    short8 kA[4], kB[4], vA[4], vB[4];
    {
      const unsigned short* Kr = K + (size_t)l31 * NDH + 8 * hi;
#pragma unroll
      for (int s = 0; s < 4; ++s) kA[s] = *(const short8*)&Kr[16 * s];
#pragma unroll
      for (int dt = 0; dt < 2; ++dt)
#pragma unroll
        for (int s = 0; s < 2; ++s)
          vA[dt * 2 + s] = *(const short8*)&V[(size_t)(dt * 32 + l31) * NT + 16 * s + 8 * hi];
    }

    auto body = [&](int kv0, int kv0n, short8 (&kc)[4], short8 (&vc)[4],
                    short8 (&kn)[4], short8 (&vn)[4]) {
      // QK^T: st[r] = S^T[k = kv0 + (r&3)+8*(r>>2)+4hi][q = q0+l31] (log2 domain)
      f32x16 st = {};
#pragma unroll
      for (int s = 0; s < 4; ++s)
        st = __builtin_amdgcn_mfma_f32_32x32x16_bf16(kc[s], qf[s], st, 0, 0, 0);
      // prefetch next kv block (K and V) into the other buffers
      {
        const unsigned short* Kr = K + (size_t)(kv0n + l31) * NDH + 8 * hi;
#pragma unroll
        for (int s = 0; s < 4; ++s) kn[s] = *(const short8*)&Kr[16 * s];
#pragma unroll
        for (int dt = 0; dt < 2; ++dt)
#pragma unroll
          for (int s = 0; s < 2; ++s)
            vn[dt * 2 + s] = *(const short8*)&V[(size_t)(dt * 32 + l31) * NT + kv0n + 16 * s + 8 * hi];
      }
      // causal mask (diagonal block only)
      if (kv0 + 32 > q0) {
        const int qg = q0 + l31;
#pragma unroll
        for (int r = 0; r < 16; ++r) {
          const int krow = kv0 + (r & 3) + 8 * (r >> 2) + 4 * hi;
          if (krow > qg) st[r] = -1e30f;
        }
      }
      // row max (16 in-lane + cross-half)
      float mx = st[0];
#pragma unroll
      for (int r = 1; r < 16; ++r) mx = fmaxf(mx, st[r]);
      mx = fmaxf(mx, __shfl_xor(mx, 32));
      // defer-max: only rescale when max grew by > 8 (P bounded by 2^8)
      if (!__all(mx - m_run <= 8.0f)) {
        const float m_new = fmaxf(m_run, mx);
        const float alpha = exp2f(m_run - m_new);
        l_run *= alpha;
        m_run = m_new;
#pragma unroll
        for (int r = 0; r < 16; ++r) { ot0[r] *= alpha; ot1[r] *= alpha; }
      }
      float pv[16];
      float ps = 0.0f;
#pragma unroll
      for (int r = 0; r < 16; ++r) {
        pv[r] = exp2f(st[r] - m_run);
        ps += pv[r];
      }
      ps += __shfl_xor(ps, 32);
      l_run += ps;
      // build PV B-fragments in-register: lane needs P^T[16s + 8hi + j][q=l31]
      short8 pf[2];
#pragma unroll
      for (int s = 0; s < 2; ++s) {
        const int o = s * 8;
        unsigned int a0 = pack2bf(pv[o + 0], pv[o + 1]);
        unsigned int a1 = pack2bf(pv[o + 2], pv[o + 3]);
        unsigned int c0 = pack2bf(pv[o + 4], pv[o + 5]);
        unsigned int c1 = pack2bf(pv[o + 6], pv[o + 7]);
        unsigned int sa0 = (unsigned int)__shfl_xor((int)a0, 32);
        unsigned int sa1 = (unsigned int)__shfl_xor((int)a1, 32);
        unsigned int sc0 = (unsigned int)__shfl_xor((int)c0, 32);
        unsigned int sc1 = (unsigned int)__shfl_xor((int)c1, 32);
        unsigned int w0 = hi ? sc0 : a0;   // j=0,1
        unsigned int w1 = hi ? sc1 : a1;   // j=2,3
        unsigned int w2 = hi ? c0 : sa0;   // j=4,5
        unsigned int w3 = hi ? c1 : sa1;   // j=6,7
        pf[s] = mkfrag(w0, w1, w2, w3);
      }
      // PV: Ot[d][q] += V^T * P^T
      ot0 = __builtin_amdgcn_mfma_f32_32x32x16_bf16(vc[0], pf[0], ot0, 0, 0, 0);
      ot0 = __builtin_amdgcn_mfma_f32_32x32x16_bf16(vc[1], pf[1], ot0, 0, 0, 0);
      ot1 = __builtin_amdgcn_mfma_f32_32x32x16_bf16(vc[2], pf[0], ot1, 0, 0, 0);
      ot1 = __builtin_amdgcn_mfma_f32_32x32x16_bf16(vc[3], pf[1], ot1, 0, 0, 0);
    };

    int kb = 0;
    while (kb < nb) {
      int kv0 = kb * 32;
      int kv0n = (kb + 1 < nb) ? kv0 + 32 : 0;
      body(kv0, kv0n, kA, vA, kB, vB);
      ++kb;
      if (kb >= nb) break;
      kv0 = kb * 32;
      kv0n = (kb + 1 < nb) ? kv0 + 32 : 0;
      body(kv0, kv0n, kB, vB, kA, vA);
      ++kb;
    }

    // epilogue: Ot[d][q] / l -> Ctx[b*T + q][h*64 + d]
    const float inv_l = 1.0f / l_run;
    unsigned short* dst = Ctx + ((size_t)(b * NT) + q0 + l31) * NDM + h * NDH;
#pragma unroll
    for (int dt = 0; dt < 2; ++dt) {
#pragma unroll
      for (int grp = 0; grp < 4; ++grp) {
        u16x4 w;
#pragma unroll
        for (int r = 0; r < 4; ++r) {
          const float v = (dt ? ot1[grp * 4 + r] : ot0[grp * 4 + r]) * inv_l;
          w[r] = f2bf(v);
        }
        *(u16x4*)&dst[dt * 32 + grp * 8 + 4 * hi] = w;
      }
    }
  }
}

extern "C" void kernel_launch(void* const* d_in, const int* in_sizes, int n_in,
                              void* d_out, int out_size, void* d_ws, size_t ws_size,
                              hipStream_t stream) {
  const float* x  = (const float*)d_in[0];
  const float* Wq = (const float*)d_in[1];
  const float* bq = (const float*)d_in[2];
  const float* Wk = (const float*)d_in[3];
  const float* bk = (const float*)d_in[4];
  const float* Wv = (const float*)d_in[5];
  const float* bv = (const float*)d_in[6];
  const float* Wo = (const float*)d_in[7];
  const float* bo = (const float*)d_in[8];

  char* ws = (char*)d_ws;
  const size_t MB = 1024 * 1024;
  if (ws_size < 105 * MB) return;

  unsigned short* XB   = (unsigned short*)(ws + 0);        // 16MB; reused as VT
  unsigned short* WQB  = (unsigned short*)(ws + 16 * MB);
  unsigned short* WKB  = (unsigned short*)(ws + 18 * MB);
  unsigned short* WVB  = (unsigned short*)(ws + 20 * MB);
  unsigned short* WOB  = (unsigned short*)(ws + 22 * MB);
  unsigned short* QBUF = (unsigned short*)(ws + 24 * MB);  // 16MB; reused as CTX
  unsigned short* KBUF = (unsigned short*)(ws + 40 * MB);
  unsigned short* VBUF = (unsigned short*)(ws + 56 * MB);
  unsigned short* QH   = (unsigned short*)(ws + 72 * MB);
  unsigned short* KH   = (unsigned short*)(ws + 88 * MB);
  float2* TAB          = (float2*)(ws + 104 * MB);         // 512KB
  unsigned short* VT = XB;
  unsigned short* CTX = QBUF;

  // converts
  k_cvt_bf16<<<(NM * NDM / 8) / 256, 256, 0, stream>>>(x, XB, NM * NDM / 8);
  dim3 gw((NDM * NDM / 8) / 256, 4);
  k_cvt_w<<<gw, 256, 0, stream>>>(Wq, Wk, Wv, Wo, WQB, WKB, WVB, WOB);
  k_rope_table<<<(NT * 32) / 256, 256, 0, stream>>>(TAB);

  // QKV projections
  dim3 gg(NDM / 128, NM / 128);
  k_gemm_bt<1><<<gg, 256, 0, stream>>>(XB, WQB, bq, QBUF, NM, NDM, NDM);
  k_gemm_bt<1><<<gg, 256, 0, stream>>>(XB, WKB, bk, KBUF, NM, NDM, NDM);
  k_gemm_bt<1><<<gg, 256, 0, stream>>>(XB, WVB, bv, VBUF, NM, NDM, NDM);

  // rope + transposes
  k_rope_apply<1><<<(NB * NT * NH) / 256, 256, 0, stream>>>(QBUF, TAB, QH);
  k_rope_apply<0><<<(NB * NT * NH) / 256, 256, 0, stream>>>(KBUF, TAB, KH);
  k_v_transpose<<<NB * NH * (NT / 64), 256, 0, stream>>>(VBUF, VT);

  // attention
  k_attn<<<NB * NH * 8, 256, 0, stream>>>(QH, KH, VT, CTX);

  // output projection (f32 out)
  k_gemm_bt<0><<<gg, 256, 0, stream>>>(CTX, WOB, bo, d_out, NM, NDM, NDM);
}